// Round 2
// baseline (146.876 us; speedup 1.0000x reference)
//
#include <hip/hip_runtime.h>
#include <hip/hip_bf16.h>

// Problem constants (from reference)
#define NN  100000   // nodes
#define DF  128      // feature dim per table
#define HD  64       // hidden dim
#define NS  250000   // samples

// ---------------------------------------------------------------------------
// Algebra (R6/R8): out[s] = w2 . relu(u'[src] + v[dst]), where
//   Pn = [in1|in2] @ B  (M=100000, K=256, N=128), bf16 (25.6 MB, L3-resident)
//   Pn[n][0:64]  = u'[n] = in1[n]@W1a + in2[n]@W1c + b1   (b1 folded)
//   Pn[n][64:128]= v [n] = in1[n]@W1b + in2[n]@W1d
//
// R14: edge frozen. GEMM post-mortem R13: transaction cut (4x), conflict cut
// (7x), occupancy +4.5pt, tail fix -> -1 us only. NOT transaction/occupancy/
// amortization-bound. Invariant across R12/R13: barrier-serialized phase
// structure (stage->barrier->MFMA per tile, 4 waves lockstepped) + 64 KB
// B-frag prologue per short block. R14 removes both:
//   - B copied global->LDS ONCE per persistent block (512 blocks, 2/CU),
//     one lgkm-barrier per block LIFETIME, zero barriers after.
//   - each WAVE independently grid-strides 16x128 output tiles; A loaded
//     straight to regs in fragment order (16 indep float4/tile, next tile
//     prefetched before MFMA phase), packed bf16 in-reg. No LDS A-staging.
//   - B-frag ds_read_b128 per (nt,ks): contiguous 1 KB/read, conflict-free.
//
// Verified MFMA layouts (gfx950, learn_hip m89/m91; R6-validated here):
//   A-frag: A[m=lane&15][k=(lane>>4)*8+j]   B-frag: B[n=lane&15][k=...]
//   C/D   : col=lane&15 (B/n side), row=(lane>>4)*4+reg (A/m side)
// LESSONS: train_sample is int32 on device; NS tail -> clamp+predicate;
// R9/R10: per-lane row-major loads scatter 16 lines/instr (transactions are
// NOT the gemm limiter per R13, so fragment-order direct loads are safe).
// ---------------------------------------------------------------------------

typedef __attribute__((ext_vector_type(8))) short bfrag;   // 8 bf16 = 4 VGPRs
typedef __attribute__((ext_vector_type(4))) float ffrag;   // 4 fp32 acc

__device__ __forceinline__ unsigned short bf16bits(float f) {
    __hip_bfloat16 b = __float2bfloat16(f);   // RNE
    return *(unsigned short*)&b;
}
__device__ __forceinline__ unsigned pack2(float a, float b) {
    return (unsigned)bf16bits(a) | ((unsigned)bf16bits(b) << 16);
}
__device__ __forceinline__ float bflo(unsigned u) {
    union { unsigned i; float f; } c; c.i = u << 16; return c.f;
}
__device__ __forceinline__ float bfhi(unsigned u) {
    union { unsigned i; float f; } c; c.i = u & 0xffff0000u; return c.f;
}
// lgkmcnt(0) only; vmcnt/expcnt left at max (gfx9 encoding) = 0xC07F
__device__ __forceinline__ void barrier_lgkm_only() {
    __builtin_amdgcn_s_waitcnt(0xC07F);
    __builtin_amdgcn_s_barrier();
}
// build a bf16x8 fragment from 8 packed floats (two float4)
__device__ __forceinline__ bfrag make_frag(const float4& a, const float4& b) {
    union { bfrag f; unsigned u[4]; } c;
    c.u[0] = pack2(a.x, a.y);
    c.u[1] = pack2(a.z, a.w);
    c.u[2] = pack2(b.x, b.y);
    c.u[3] = pack2(b.z, b.w);
    return c.f;
}

// ---- prep: pack B (256x128) into fragment-ordered bf16; pack w2 bf16 ----
// Bf[tn][ks][lane][j]: n = tn*16+(lane&15), k = ks*32+(lane>>4)*8+j
__global__ __launch_bounds__(256) void prep_w1_kernel(
    const float* __restrict__ w1, const float* __restrict__ w2,
    unsigned short* __restrict__ Bf, unsigned short* __restrict__ w2bf)
{
    const int gid = blockIdx.x * 256 + threadIdx.x;
    if (gid >= 4096) {
        const int j = gid - 4096;
        if (j < HD) w2bf[j] = bf16bits(w2[j]);
        return;
    }
    const int lane = gid & 63;
    const int ks   = (gid >> 6) & 7;
    const int tn   = gid >> 9;

    const int n     = tn * 16 + (lane & 15);
    const int kbase = ks * 32 + (lane >> 4) * 8;
    const int col   = n & 63;

    uint4 u;
    unsigned p[4];
    #pragma unroll
    for (int jp = 0; jp < 4; ++jp) {
        float v[2];
        #pragma unroll
        for (int h = 0; h < 2; ++h) {
            const int k = kbase + jp * 2 + h;
            const int row = ((k >= 128) ? 256 : 0) + ((n >= 64) ? 128 : 0) + (k & 127);
            v[h] = w1[(size_t)row * HD + col];
        }
        p[jp] = pack2(v[0], v[1]);
    }
    u.x = p[0]; u.y = p[1]; u.z = p[2]; u.w = p[3];
    *(uint4*)(Bf + (size_t)gid * 8) = u;
}

#define GBLK   512                 // persistent blocks (2/CU at ~70 KB LDS)
#define NWAVE  (GBLK * 4)          // 2048 waves
#define NTILES (NN / 16)           // 6250 row-tiles

// ---- phase 1 (R14): barrier-free wave-streaming MFMA GEMM ----
__global__ __launch_bounds__(256) void node_gemm_mfma(
    const float* __restrict__ in1,
    const float* __restrict__ in2,
    const unsigned short* __restrict__ Bf,
    const float* __restrict__ b1,
    unsigned short* __restrict__ Pn)         // [NN][128] bf16
{
    // 64 KB B fragments + 4 x 1152 B per-wave epilogue scratch
    __shared__ unsigned short smem[32768 + 4 * 576];

    const int t    = threadIdx.x;
    const int lane = t & 63;
    const int w    = t >> 6;

    const int m    = lane & 15;        // A/C row within tile
    const int koff = (lane >> 4) * 8;  // A k-chunk base within 32-slice

    int mt = blockIdx.x * 4 + w;       // this wave's first tile

    // issue first A tile loads BEFORE the B copy so they overlap it
    float4 cur[16];
    if (mt < NTILES) {
        const float* r1 = in1 + (size_t)(mt * 16 + m) * DF + koff;
        const float* r2 = in2 + (size_t)(mt * 16 + m) * DF + koff;
        #pragma unroll
        for (int s = 0; s < 4; ++s) {
            cur[s * 2]     = *(const float4*)(r1 + s * 32);
            cur[s * 2 + 1] = *(const float4*)(r1 + s * 32 + 4);
            cur[8 + s * 2] = *(const float4*)(r2 + s * 32);
            cur[9 + s * 2] = *(const float4*)(r2 + s * 32 + 4);
        }
    }

    // cooperative copy of the 64 KB fragment-ordered B into LDS (once)
    {
        const uint4* src = (const uint4*)Bf;
        uint4* dst = (uint4*)smem;
        #pragma unroll
        for (int i = 0; i < 16; ++i)
            dst[t + i * 256] = src[t + i * 256];
    }

    // bias for column tiles 0..3 (u'-half); v-half (nt>=4) has no bias
    float badd[4];
    #pragma unroll
    for (int nt = 0; nt < 4; ++nt) badd[nt] = b1[nt * 16 + m];

    barrier_lgkm_only();   // B visible; A loads stay in flight (no vmcnt drain)

    unsigned short* ep = &smem[32768 + w * 576];   // wave-private 16x36

    for (; mt < NTILES; mt += NWAVE) {
        // pack current A tile into fragments (frees cur f32 regs)
        bfrag af[8];
        #pragma unroll
        for (int s = 0; s < 4; ++s) {
            af[s]     = make_frag(cur[s * 2],     cur[s * 2 + 1]);
            af[4 + s] = make_frag(cur[8 + s * 2], cur[9 + s * 2]);
        }

        // prefetch next tile (wave-uniform guard)
        const int mtn = mt + NWAVE;
        if (mtn < NTILES) {
            const float* r1 = in1 + (size_t)(mtn * 16 + m) * DF + koff;
            const float* r2 = in2 + (size_t)(mtn * 16 + m) * DF + koff;
            #pragma unroll
            for (int s = 0; s < 4; ++s) {
                cur[s * 2]     = *(const float4*)(r1 + s * 32);
                cur[s * 2 + 1] = *(const float4*)(r1 + s * 32 + 4);
                cur[8 + s * 2] = *(const float4*)(r2 + s * 32);
                cur[9 + s * 2] = *(const float4*)(r2 + s * 32 + 4);
            }
        }

        // 16x128 output tile: 8 column tiles x 8 k-slices, B from LDS
        ffrag acc[8];
        #pragma unroll
        for (int nt = 0; nt < 8; ++nt) acc[nt] = ffrag{0.f, 0.f, 0.f, 0.f};

        #pragma unroll
        for (int ks = 0; ks < 8; ++ks) {
            #pragma unroll
            for (int nt = 0; nt < 8; ++nt) {
                const bfrag bf = *(const bfrag*)(&smem[((nt * 8 + ks) * 64 + lane) * 8]);
                acc[nt] = __builtin_amdgcn_mfma_f32_16x16x32_bf16(af[ks], bf, acc[nt], 0, 0, 0);
            }
        }

        // epilogue: per-wave private LDS transpose, 2 column tiles per pass
        const int m0   = mt * 16;
        const int col  = lane & 15;
        const int rq   = lane >> 4;
        const int rowm = lane >> 2;
        const int seg  = lane & 3;
        #pragma unroll
        for (int p = 0; p < 4; ++p) {
            #pragma unroll
            for (int h = 0; h < 2; ++h) {
                const int nt = p * 2 + h;
                #pragma unroll
                for (int reg = 0; reg < 4; ++reg) {
                    const float v = acc[nt][reg] + ((nt < 4) ? badd[nt] : 0.f);
                    ep[(rq * 4 + reg) * 36 + h * 16 + col] = bf16bits(v);
                }
            }
            const uint4 u = *(const uint4*)(&ep[rowm * 36 + seg * 8]);
            *(uint4*)(Pn + (size_t)(m0 + rowm) * 128 + p * 32 + seg * 8) = u;
        }
    }
}

// ---- phase 2 (R12, frozen): persistent gather MLP, dep-chain pipelined ----
// grid = 1024 blocks x 256 threads, 4 passes. Pass p of block b handles
// samples [ (p*1024 + b)*64, +64 ): 4 lanes/sample, 16 cols/lane.
// w2 slice hoisted to regs; next pass's ts load issues before current
// gathers are consumed -> every wave keeps ~5 independent VMEM in flight.
#define EBLK   1024
#define EPASS  4     // ceil(250000 / (1024*64)) = 4
__global__ __launch_bounds__(256) void edge_mlp_kernel(
    const unsigned short* __restrict__ Pn,
    const int*   __restrict__ ts,     // train_sample, int32
    const unsigned short* __restrict__ w2bf,   // 64 bf16
    float* __restrict__ out)          // (250000)
{
    const int t = threadIdx.x;
    const int q = t & 3;          // 16-col slice: cols q*16 .. q*16+15
    const int g = t >> 2;         // sample slot 0..63

    // hoist w2 slice (32 B) into registers once
    const uint4 w0 = *(const uint4*)(w2bf + q * 16);
    const uint4 w1v = *(const uint4*)(w2bf + q * 16 + 8);

    const int2* ts2 = (const int2*)ts;

    int sr = blockIdx.x * 64 + g;             // pass 0 sample
    int2 e = ts2[min(sr, NS - 1)];

    #pragma unroll
    for (int p = 0; p < EPASS; ++p) {
        // gathers for current sample (independent 16B loads)
        const unsigned short* up = Pn + (size_t)e.x * 128 + q * 16;
        const unsigned short* vp = Pn + (size_t)e.y * 128 + 64 + q * 16;
        const uint4 u0 = *(const uint4*)(up);
        const uint4 u1 = *(const uint4*)(up + 8);
        const uint4 v0 = *(const uint4*)(vp);
        const uint4 v1 = *(const uint4*)(vp + 8);

        // issue next pass's ts load BEFORE consuming the gathers
        const int sr_n = sr + EBLK * 64;
        int2 e_n;
        if (p + 1 < EPASS) e_n = ts2[min(sr_n, NS - 1)];

        float acc = 0.f, x;
        x = bflo(u0.x) + bflo(v0.x); x = x > 0.f ? x : 0.f; acc += x * bflo(w0.x);
        x = bfhi(u0.x) + bfhi(v0.x); x = x > 0.f ? x : 0.f; acc += x * bfhi(w0.x);
        x = bflo(u0.y) + bflo(v0.y); x = x > 0.f ? x : 0.f; acc += x * bflo(w0.y);
        x = bfhi(u0.y) + bfhi(v0.y); x = x > 0.f ? x : 0.f; acc += x * bfhi(w0.y);
        x = bflo(u0.z) + bflo(v0.z); x = x > 0.f ? x : 0.f; acc += x * bflo(w0.z);
        x = bfhi(u0.z) + bfhi(v0.z); x = x > 0.f ? x : 0.f; acc += x * bfhi(w0.z);
        x = bflo(u0.w) + bflo(v0.w); x = x > 0.f ? x : 0.f; acc += x * bflo(w0.w);
        x = bfhi(u0.w) + bfhi(v0.w); x = x > 0.f ? x : 0.f; acc += x * bfhi(w0.w);
        x = bflo(u1.x) + bflo(v1.x); x = x > 0.f ? x : 0.f; acc += x * bflo(w1v.x);
        x = bfhi(u1.x) + bfhi(v1.x); x = x > 0.f ? x : 0.f; acc += x * bfhi(w1v.x);
        x = bflo(u1.y) + bflo(v1.y); x = x > 0.f ? x : 0.f; acc += x * bflo(w1v.y);
        x = bfhi(u1.y) + bfhi(v1.y); x = x > 0.f ? x : 0.f; acc += x * bfhi(w1v.y);
        x = bflo(u1.z) + bflo(v1.z); x = x > 0.f ? x : 0.f; acc += x * bflo(w1v.z);
        x = bfhi(u1.z) + bfhi(v1.z); x = x > 0.f ? x : 0.f; acc += x * bfhi(w1v.z);
        x = bflo(u1.w) + bflo(v1.w); x = x > 0.f ? x : 0.f; acc += x * bflo(w1v.w);
        x = bfhi(u1.w) + bfhi(v1.w); x = x > 0.f ? x : 0.f; acc += x * bfhi(w1v.w);

        acc += __shfl_xor(acc, 1);
        acc += __shfl_xor(acc, 2);
        if (q == 0 && sr < NS) out[sr] = acc;

        sr = sr_n;
        e  = e_n;
    }
}

extern "C" void kernel_launch(void* const* d_in, const int* in_sizes, int n_in,
                              void* d_out, int out_size, void* d_ws, size_t ws_size,
                              hipStream_t stream) {
    const float* in1 = (const float*)d_in[0];
    const float* in2 = (const float*)d_in[1];
    const int*   ts  = (const int*)  d_in[2];
    const float* w1  = (const float*)d_in[3];
    const float* b1  = (const float*)d_in[4];
    const float* w2  = (const float*)d_in[5];
    float* out = (float*)d_out;

    unsigned short* Pn = (unsigned short*)d_ws;     // 100000*128*2 = 25.6 MB
    const size_t Pbytes = (size_t)NN * 128 * sizeof(unsigned short);
    unsigned short* Bf;                             // 64 KB packed-B fragments
    unsigned short* w2bf;                           // 128 B packed w2
    if (ws_size >= Pbytes + 65536 + 128) {
        Bf   = (unsigned short*)((char*)d_ws + Pbytes);
        w2bf = (unsigned short*)((char*)d_ws + Pbytes + 65536);
    } else {
        // fallback: borrow d_out front (fully overwritten by phase 2)
        Bf   = (unsigned short*)d_out;
        w2bf = (unsigned short*)((char*)d_out + 65536);
    }

    prep_w1_kernel<<<17, 256, 0, stream>>>(w1, w2, Bf, w2bf);
    node_gemm_mfma<<<GBLK, 256, 0, stream>>>(in1, in2, Bf, b1, Pn);
    edge_mlp_kernel<<<EBLK, 256, 0, stream>>>(Pn, ts, w2bf, out);
}